// Round 1
// baseline (173.221 us; speedup 1.0000x reference)
//
#include <hip/hip_runtime.h>
#include <stdint.h>

typedef short s8v __attribute__((ext_vector_type(8)));   // 8 x bf16 (4 VGPRs)
typedef float f4v __attribute__((ext_vector_type(4)));   // MFMA accumulator

#define EMB_DIM 256
#define N_EMBED 1024
#define BATCH   32
#define HW      1024                  // 32*32 spatial per batch
#define NROWS   (BATCH * HW)          // 32768
#define NELEM   (NROWS * EMB_DIM)     // 8388608

__device__ __forceinline__ unsigned short f2bf(float f) {
    union { float f; unsigned u; } c; c.f = f;
    unsigned u = c.u;
    return (unsigned short)((u + 0x7FFFu + ((u >> 16) & 1u)) >> 16);  // RNE
}

// ---------------------------------------------------------------------------
// prep: codebook fp32 -> bf16 packed in B-fragment streaming order, plus ||e||^2
// pk element (T, s, lane, j) = cb[T*16 + (lane&15)][32*s + 8*(lane>>4) + j]
// ---------------------------------------------------------------------------
__global__ void prep_kernel(const float* __restrict__ cb,
                            unsigned short* __restrict__ pk,
                            float* __restrict__ cbn,
                            double* __restrict__ gacc) {
    int c = blockIdx.x;      // code row 0..1023
    int t = threadIdx.x;     // dim 0..255
    float v = cb[c * EMB_DIM + t];
    int T = c >> 4, ci = c & 15;
    int s = t >> 5, G = (t >> 3) & 3, j = t & 7;
    pk[(((size_t)(T * 8 + s) * 64) + (G * 16 + ci)) * 8 + j] = f2bf(v);

    float sq = v * v;
    #pragma unroll
    for (int m = 1; m < 64; m <<= 1) sq += __shfl_xor(sq, m, 64);
    __shared__ float wsum[4];
    if ((t & 63) == 0) wsum[t >> 6] = sq;
    __syncthreads();
    if (t == 0) {
        cbn[c] = wsum[0] + wsum[1] + wsum[2] + wsum[3];
        if (blockIdx.x == 0) *gacc = 0.0;
    }
}

// ---------------------------------------------------------------------------
// main: copy x->out, per-row min distance via bf16 MFMA, accumulate loss sum
// block = 256 thr (4 waves); block covers batch b, 64 spatial positions
// wave w covers 16 rows: p0 + 16w + (lane&15)
// ---------------------------------------------------------------------------
__global__ __launch_bounds__(256) void vq_main(const float* __restrict__ x,
                                               float* __restrict__ out,
                                               const unsigned short* __restrict__ pk,
                                               const float* __restrict__ cbn,
                                               double* __restrict__ gacc) {
    __shared__ float xnp[16][64];
    __shared__ float xnorm[64];
    __shared__ float bsum;

    int t  = threadIdx.x;
    int b  = blockIdx.x >> 4;
    int p0 = (blockIdx.x & 15) << 6;
    const float* xb = x   + (size_t)b * (EMB_DIM * HW) + p0;
    float*       ob = out + (size_t)b * (EMB_DIM * HW) + p0;

    // ---- pass 1: copy + ||x||^2 partials (float4, fully coalesced) ----
    int tp = t & 15, dr = t >> 4;      // thread covers p = 4*tp..4*tp+3, d = dr + 16i
    float pa0 = 0.f, pa1 = 0.f, pa2 = 0.f, pa3 = 0.f;
    #pragma unroll 4
    for (int i = 0; i < 16; ++i) {
        int d = dr + 16 * i;
        const float4 v = *(const float4*)(xb + (size_t)d * HW + 4 * tp);
        *(float4*)(ob + (size_t)d * HW + 4 * tp) = v;
        pa0 += v.x * v.x; pa1 += v.y * v.y; pa2 += v.z * v.z; pa3 += v.w * v.w;
    }
    xnp[dr][4 * tp + 0] = pa0;
    xnp[dr][4 * tp + 1] = pa1;
    xnp[dr][4 * tp + 2] = pa2;
    xnp[dr][4 * tp + 3] = pa3;
    if (t == 0) bsum = 0.f;
    __syncthreads();
    if (t < 64) {
        float s = 0.f;
        #pragma unroll
        for (int k = 0; k < 16; ++k) s += xnp[k][t];
        xnorm[t] = s;
    }
    __syncthreads();

    // ---- pass 2: A-fragments straight from L2 (slab is hot from pass 1) ----
    int l = t & 63, w = t >> 6;
    int G = l >> 4, ci = l & 15;
    const float* ax = x + (size_t)b * (EMB_DIM * HW) + (p0 + 16 * w + ci);
    s8v a[8];
    #pragma unroll
    for (int s = 0; s < 8; ++s) {
        #pragma unroll
        for (int j = 0; j < 8; ++j) {
            a[s][j] = (short)f2bf(ax[(size_t)(32 * s + 8 * G + j) * HW]);
        }
    }

    // ---- hot loop: 64 code-tiles x (8 B-loads + 8 MFMA) ----
    float mv[4] = {1e30f, 1e30f, 1e30f, 1e30f};
    const char* pb = (const char*)pk + l * 16;
    for (int T = 0; T < 64; ++T) {
        const char* pt = pb + (size_t)T * 8192;
        f4v acc = {0.f, 0.f, 0.f, 0.f};
        #pragma unroll
        for (int s = 0; s < 8; ++s) {
            s8v bf = *(const s8v*)(pt + s * 1024);
            acc = __builtin_amdgcn_mfma_f32_16x16x32_bf16(a[s], bf, acc, 0, 0, 0);
        }
        float cv = cbn[(T << 4) + ci];            // ||e||^2 for this lane's code
        #pragma unroll
        for (int r = 0; r < 4; ++r)
            mv[r] = fminf(mv[r], cv - 2.0f * acc[r]);
    }

    // ---- reduce: min over the 16 code-lanes sharing the same rows ----
    #pragma unroll
    for (int r = 0; r < 4; ++r) {
        #pragma unroll
        for (int m = 1; m < 16; m <<= 1)
            mv[r] = fminf(mv[r], __shfl_xor(mv[r], m, 64));
    }
    // rows of this lane-group: 16w + 4G + r ; value identical within 16-lane group
    float part = 0.f;
    #pragma unroll
    for (int r = 0; r < 4; ++r)
        part += xnorm[16 * w + 4 * G + r] + mv[r];
    part += __shfl_xor(part, 16, 64);   // sum the 4 lane-groups (uniform in group)
    part += __shfl_xor(part, 32, 64);
    if (l == 0) atomicAdd(&bsum, part);
    __syncthreads();
    if (t == 0) atomicAdd(gacc, (double)bsum);
}

// ---------------------------------------------------------------------------
__global__ void fin_kernel(const double* __restrict__ gacc, float* __restrict__ out) {
    double cl = *gacc / (double)NELEM;
    out[NELEM + 0] = (float)(1.25 * cl);   // loss = codebook + 0.25*commitment
    out[NELEM + 1] = (float)cl;            // codebook_loss
    out[NELEM + 2] = (float)cl;            // commitment_loss (== codebook_loss fwd)
}

extern "C" void kernel_launch(void* const* d_in, const int* in_sizes, int n_in,
                              void* d_out, int out_size, void* d_ws, size_t ws_size,
                              hipStream_t stream) {
    const float* enc = (const float*)d_in[0];
    const float* cb  = (const float*)d_in[1];
    float* out = (float*)d_out;

    unsigned short* pk  = (unsigned short*)d_ws;                       // 512 KB packed bf16 codebook
    float*          cbn = (float*)((char*)d_ws + 524288);              // 4 KB norms
    double*         gac = (double*)((char*)d_ws + 524288 + 4096);      // 8 B accumulator

    prep_kernel<<<N_EMBED, EMB_DIM, 0, stream>>>(cb, pk, cbn, gac);
    vq_main<<<512, 256, 0, stream>>>(enc, out, pk, cbn, gac);
    fin_kernel<<<1, 1, 0, stream>>>(gac, out);
}

// Round 2
// 150.674 us; speedup vs baseline: 1.1496x; 1.1496x over previous
//
#include <hip/hip_runtime.h>
#include <stdint.h>

typedef short s8v __attribute__((ext_vector_type(8)));   // 8 x bf16 (4 VGPRs)
typedef float f4v __attribute__((ext_vector_type(4)));   // MFMA accumulator

#define EMB_DIM 256
#define N_EMBED 1024
#define HW      1024
#define NROWS   32768
#define NELEM   (NROWS * EMB_DIM)     // 8388608

__device__ __forceinline__ unsigned short f2bf(float f) {
    union { float f; unsigned u; } c; c.f = f;
    unsigned u = c.u;
    return (unsigned short)((u + 0x7FFFu + ((u >> 16) & 1u)) >> 16);  // RNE
}

// ---------------------------------------------------------------------------
// prep_pack: block T (64 blocks) packs 16 codes x 256 dims into B-fragment
// order with fully coalesced 16B writes, and computes ||e||^2.
// pk byte (T,s,lane,j): cb[T*16 + (lane&15)][32s + 8*(lane>>4) + j]
// ---------------------------------------------------------------------------
__global__ void prep_pack(const float* __restrict__ cb,
                          unsigned short* __restrict__ pk,
                          float* __restrict__ cbn) {
    __shared__ float cbs[16][260];   // +4 pad: conflict-free packed reads
    __shared__ float nrm[16][17];
    int T = blockIdx.x, t = threadIdx.x;
    int code = t >> 4, seg = t & 15;
    const float* src = cb + (size_t)(T * 16 + code) * EMB_DIM + seg * 16;
    float s2 = 0.f;
    #pragma unroll
    for (int k = 0; k < 4; ++k) {
        float4 v = *(const float4*)(src + 4 * k);
        cbs[code][seg * 16 + 4 * k + 0] = v.x;
        cbs[code][seg * 16 + 4 * k + 1] = v.y;
        cbs[code][seg * 16 + 4 * k + 2] = v.z;
        cbs[code][seg * 16 + 4 * k + 3] = v.w;
        s2 += v.x * v.x + v.y * v.y + v.z * v.z + v.w * v.w;
    }
    nrm[code][seg] = s2;
    __syncthreads();
    if (t < 16) {
        float s = 0.f;
        #pragma unroll
        for (int k = 0; k < 16; ++k) s += nrm[t][k];
        cbn[T * 16 + t] = s;
    }
    #pragma unroll
    for (int it = 0; it < 2; ++it) {
        int idx = t + 256 * it;
        int s = idx >> 6, lp = idx & 63, G = lp >> 4, ci = lp & 15;
        const float* q = &cbs[ci][32 * s + 8 * G];
        unsigned o0, o1, o2, o3;
        o0 = (unsigned)f2bf(q[0]) | ((unsigned)f2bf(q[1]) << 16);
        o1 = (unsigned)f2bf(q[2]) | ((unsigned)f2bf(q[3]) << 16);
        o2 = (unsigned)f2bf(q[4]) | ((unsigned)f2bf(q[5]) << 16);
        o3 = (unsigned)f2bf(q[6]) | ((unsigned)f2bf(q[7]) << 16);
        *(uint4*)((char*)pk + (size_t)T * 8192 + (size_t)idx * 16) =
            make_uint4(o0, o1, o2, o3);
    }
}

// ---------------------------------------------------------------------------
// vq_dist: grid = 256 row-blocks x 4 code-splits.  Block = 4 waves.
// Block covers 128 rows x 256 codes (its quarter of the codebook).
// Wave w covers rows p0+32w..+31 (2 row-tiles of 16), writes per-row partial
// min of (||e||^2 - 2 x.e) into rp[c][row].  c==0 blocks also copy x->out
// and emit per-row ||x||^2 (overlapped with other splits' compute).
// ---------------------------------------------------------------------------
__global__ __launch_bounds__(256, 4) void vq_dist(const float* __restrict__ x,
                                                  float* __restrict__ out,
                                                  const unsigned short* __restrict__ pk,
                                                  const float* __restrict__ cbn,
                                                  float* __restrict__ xn,
                                                  float* __restrict__ rp) {
    __shared__ float xs[256][4];
    int t = threadIdx.x;
    int rowblk = blockIdx.x >> 2;
    int c = blockIdx.x & 3;
    int b = rowblk >> 3;
    int p0 = (rowblk & 7) << 7;
    const float* xb = x + (size_t)b * (EMB_DIM * HW);

    if (c == 0) {
        // copy the 256d x 128p slab + per-row ||x||^2
        float* ob = out + (size_t)b * (EMB_DIM * HW);
        int p4 = t & 31, dsub = t >> 5;
        float a0 = 0.f, a1 = 0.f, a2 = 0.f, a3 = 0.f;
        #pragma unroll 8
        for (int i = 0; i < 32; ++i) {
            int d = dsub + 8 * i;
            const float4 v = *(const float4*)(xb + (size_t)d * HW + p0 + 4 * p4);
            *(float4*)(ob + (size_t)d * HW + p0 + 4 * p4) = v;
            a0 += v.x * v.x; a1 += v.y * v.y; a2 += v.z * v.z; a3 += v.w * v.w;
        }
        xs[t][0] = a0; xs[t][1] = a1; xs[t][2] = a2; xs[t][3] = a3;
        __syncthreads();
        if (t < 128) {
            int pq = t >> 2, comp = t & 3;
            float s = 0.f;
            #pragma unroll
            for (int k = 0; k < 8; ++k) s += xs[pq + 32 * k][comp];
            xn[b * HW + p0 + t] = s;
        }
    }

    // ---- A fragments: 2 row-tiles, full K=256, fp32 strided -> bf16 ----
    int l = t & 63, w = t >> 6;
    int G = l >> 4, ci = l & 15;
    const float* ax = xb + p0 + 32 * w + ci;
    s8v a0[8], a1[8];
    #pragma unroll
    for (int s = 0; s < 8; ++s) {
        #pragma unroll
        for (int j = 0; j < 8; ++j) {
            int d = 32 * s + 8 * G + j;
            a0[s][j] = (short)f2bf(ax[(size_t)d * HW]);
            a1[s][j] = (short)f2bf(ax[(size_t)d * HW + 16]);
        }
    }

    // ---- hot loop: 16 code-tiles, 8 B-loads feed 16 MFMAs (2 indep chains)
    float mv0[4] = {1e30f, 1e30f, 1e30f, 1e30f};
    float mv1[4] = {1e30f, 1e30f, 1e30f, 1e30f};
    const char* pb = (const char*)pk + (size_t)(c * 16) * 8192 + l * 16;
    #pragma unroll 2
    for (int T = 0; T < 16; ++T) {
        const char* pt = pb + (size_t)T * 8192;
        f4v ac0 = {0.f, 0.f, 0.f, 0.f};
        f4v ac1 = {0.f, 0.f, 0.f, 0.f};
        #pragma unroll
        for (int s = 0; s < 8; ++s) {
            s8v bf = *(const s8v*)(pt + s * 1024);
            ac0 = __builtin_amdgcn_mfma_f32_16x16x32_bf16(a0[s], bf, ac0, 0, 0, 0);
            ac1 = __builtin_amdgcn_mfma_f32_16x16x32_bf16(a1[s], bf, ac1, 0, 0, 0);
        }
        float cv = cbn[(c * 16 + T) * 16 + ci];
        #pragma unroll
        for (int r = 0; r < 4; ++r) {
            mv0[r] = fminf(mv0[r], cv - 2.f * ac0[r]);
            mv1[r] = fminf(mv1[r], cv - 2.f * ac1[r]);
        }
    }

    // ---- min over the 16 code-lanes; write per-row partials ----
    #pragma unroll
    for (int r = 0; r < 4; ++r) {
        #pragma unroll
        for (int m = 1; m < 16; m <<= 1) {
            mv0[r] = fminf(mv0[r], __shfl_xor(mv0[r], m, 64));
            mv1[r] = fminf(mv1[r], __shfl_xor(mv1[r], m, 64));
        }
    }
    if (ci == 0) {
        int base = c * NROWS + b * HW + p0 + 32 * w;
        #pragma unroll
        for (int r = 0; r < 4; ++r) {
            rp[base +      4 * G + r] = mv0[r];
            rp[base + 16 + 4 * G + r] = mv1[r];
        }
    }
}

// ---------------------------------------------------------------------------
// fin: single block; min over the 4 partials + ||x||^2, double-sum, scalars.
// ---------------------------------------------------------------------------
__global__ void fin_kernel(const float* __restrict__ rp,
                           const float* __restrict__ xn,
                           float* __restrict__ out) {
    int t = threadIdx.x;
    double s = 0.0;
    for (int i = 0; i < 32; ++i) {
        int r = t + 1024 * i;
        float m01 = fminf(rp[r], rp[NROWS + r]);
        float m23 = fminf(rp[2 * NROWS + r], rp[3 * NROWS + r]);
        s += (double)(fminf(m01, m23) + xn[r]);
    }
    #pragma unroll
    for (int m = 1; m < 64; m <<= 1) s += __shfl_xor(s, m, 64);
    __shared__ double ds[16];
    if ((t & 63) == 0) ds[t >> 6] = s;
    __syncthreads();
    if (t == 0) {
        double tot = 0.0;
        for (int k = 0; k < 16; ++k) tot += ds[k];
        double cl = tot / (double)NELEM;
        out[NELEM + 0] = (float)(1.25 * cl);
        out[NELEM + 1] = (float)cl;
        out[NELEM + 2] = (float)cl;
    }
}

extern "C" void kernel_launch(void* const* d_in, const int* in_sizes, int n_in,
                              void* d_out, int out_size, void* d_ws, size_t ws_size,
                              hipStream_t stream) {
    const float* enc = (const float*)d_in[0];
    const float* cb  = (const float*)d_in[1];
    float* out = (float*)d_out;

    unsigned short* pk  = (unsigned short*)d_ws;                 // 512 KB packed bf16 codebook
    float* cbn = (float*)((char*)d_ws + 524288);                 // 4 KB ||e||^2
    float* xn  = (float*)((char*)d_ws + 528384);                 // 128 KB per-row ||x||^2
    float* rp  = (float*)((char*)d_ws + 659456);                 // 512 KB partial mins [4][32768]

    prep_pack<<<64, 256, 0, stream>>>(cb, pk, cbn);
    vq_dist<<<1024, 256, 0, stream>>>(enc, out, pk, cbn, xn, rp);
    fin_kernel<<<1, 1024, 0, stream>>>(rp, xn, out);
}

// Round 3
// 137.922 us; speedup vs baseline: 1.2559x; 1.0925x over previous
//
#include <hip/hip_runtime.h>
#include <stdint.h>

typedef short s8v __attribute__((ext_vector_type(8)));   // 8 x bf16 (4 VGPRs)
typedef float f4v __attribute__((ext_vector_type(4)));   // MFMA accumulator

#define EMB_DIM 256
#define N_EMBED 1024
#define HW      1024
#define NROWS   32768
#define NELEM   (NROWS * EMB_DIM)     // 8388608
#define NSPLIT  8                     // code splits (128 codes each)

// ws layout (bytes)
#define PK_OFF   0u          // 512 KB packed bf16 codebook
#define CBN_OFF  524288u     // 4 KB ||e||^2
#define PSUM_OFF 528384u     // 8 KB per-block sum(x^2) partials [2048]
#define RP_OFF   536576u     // 1 MB per-row partial mins [8][32768]
#define XPK_OFF  1585152u    // 16 MB packed bf16 x fragments
#define XPK_BYTES (2048u * 8u * 64u * 16u)
#define WS_NEED  (XPK_OFF + XPK_BYTES)

__device__ __forceinline__ unsigned f2bf(float f) {
    union { float f; unsigned u; } c; c.f = f;
    unsigned u = c.u;
    return (u + 0x7FFFu + ((u >> 16) & 1u)) >> 16;   // RNE
}

// ---------------------------------------------------------------------------
// pack_all: blocks 0..2047 copy x->out (coalesced), accumulate per-block
// sum(x^2), and (PACKED) transpose-convert x into bf16 A-fragments xpk.
// Blocks 2048..2111 pack the codebook into B-fragments + compute ||e||^2.
//
// xpk layout: frag(R,s,lane l=G*16+ci, j) = x_row[R*16+ci][d=32s+8G+j]
//             stored at uint4 index (R*8+s)*64 + l
// ---------------------------------------------------------------------------
template<bool PACKED>
__global__ __launch_bounds__(256) void pack_all(const float* __restrict__ x,
                                                const float* __restrict__ cb,
                                                float* __restrict__ out,
                                                unsigned short* __restrict__ pk,
                                                float* __restrict__ cbn,
                                                float* __restrict__ psum,
                                                uint4* __restrict__ xpk) {
    int t = threadIdx.x;

    if (blockIdx.x >= 2048) {
        // ---- codebook role ----
        int T = blockIdx.x - 2048;          // tile of 16 codes
        {   // ||e||^2: thread covers code t>>4, dims (t&15)*16 .. +15
            int code = t >> 4, seg = t & 15;
            const float* src = cb + (size_t)(T * 16 + code) * EMB_DIM + seg * 16;
            float s2 = 0.f;
            #pragma unroll
            for (int k = 0; k < 4; ++k) {
                float4 v = *(const float4*)(src + 4 * k);
                s2 += v.x * v.x + v.y * v.y + v.z * v.z + v.w * v.w;
            }
            #pragma unroll
            for (int m = 1; m < 16; m <<= 1) s2 += __shfl_xor(s2, m, 64);
            if (seg == 0) cbn[T * 16 + code] = s2;
        }
        // pack: frag(T,s,l,j) = cb[T*16+ci][32s+8G+j]
        #pragma unroll
        for (int it = 0; it < 2; ++it) {
            int idx = t + 256 * it;
            int s = idx >> 6, l = idx & 63, G = l >> 4, ci = l & 15;
            const float* q = cb + (size_t)(T * 16 + ci) * EMB_DIM + 32 * s + 8 * G;
            float4 v0 = *(const float4*)(q);
            float4 v1 = *(const float4*)(q + 4);
            unsigned o0 = f2bf(v0.x) | (f2bf(v0.y) << 16);
            unsigned o1 = f2bf(v0.z) | (f2bf(v0.w) << 16);
            unsigned o2 = f2bf(v1.x) | (f2bf(v1.y) << 16);
            unsigned o3 = f2bf(v1.z) | (f2bf(v1.w) << 16);
            *(uint4*)((char*)pk + (size_t)T * 8192 + (size_t)idx * 16) =
                make_uint4(o0, o1, o2, o3);
        }
        return;
    }

    // ---- x role: 64 dims x 64 spatial tile ----
    __shared__ float smem[4448];        // [64][69] + wsum[4] @4440
    int id = blockIdx.x;
    int b = id >> 6, rest = id & 63;
    int dc = rest >> 4, pc = rest & 15; // d-chunk(64), p-chunk(64)
    int D0 = dc * 64, P0 = pc * 64;
    const float* xb = x   + (size_t)b * (EMB_DIM * HW);
    float*       ob = out + (size_t)b * (EMB_DIM * HW);

    int r = t >> 4, q = t & 15;
    float sq = 0.f;
    #pragma unroll
    for (int kd = 0; kd < 4; ++kd) {
        int d = D0 + 16 * kd + r;
        size_t off = (size_t)d * HW + P0 + 4 * q;
        float4 v = *(const float4*)(xb + off);
        *(float4*)(ob + off) = v;
        if (PACKED) {
            float* dst = &smem[(16 * kd + r) * 69 + 4 * q];
            dst[0] = v.x; dst[1] = v.y; dst[2] = v.z; dst[3] = v.w;
        }
        sq += v.x * v.x + v.y * v.y + v.z * v.z + v.w * v.w;
    }
    #pragma unroll
    for (int m = 1; m < 64; m <<= 1) sq += __shfl_xor(sq, m, 64);
    if ((t & 63) == 0) smem[4440 + (t >> 6)] = sq;
    __syncthreads();
    if (t == 0) psum[id] = smem[4440] + smem[4441] + smem[4442] + smem[4443];

    if (PACKED) {
        // 512 fragments of 8 bf16: (tau 0..3) x (sL 0..1) x (lane 0..63)
        #pragma unroll
        for (int it = 0; it < 2; ++it) {
            int f = t + 256 * it;
            int l = f & 63, sL = (f >> 6) & 1, tau = f >> 7;
            int G = l >> 4, ci = l & 15;
            const float* qq = &smem[(32 * sL + 8 * G) * 69 + 16 * tau + ci];
            unsigned o0 = f2bf(qq[0])   | (f2bf(qq[69])  << 16);
            unsigned o1 = f2bf(qq[138]) | (f2bf(qq[207]) << 16);
            unsigned o2 = f2bf(qq[276]) | (f2bf(qq[345]) << 16);
            unsigned o3 = f2bf(qq[414]) | (f2bf(qq[483]) << 16);
            int R = b * 64 + 4 * pc + tau;      // global row-tile
            xpk[((size_t)R * 8 + 2 * dc + sL) * 64 + l] =
                make_uint4(o0, o1, o2, o3);
        }
    }
}

// ---------------------------------------------------------------------------
// vq_dist: grid = 256 rowblocks x 8 code-splits. Block = 4 waves; wave owns
// 2 row-tiles (32 rows), computes min_k(||e||^2 - 2 x.e) over its 128 codes,
// writes per-row partials rp[c][row].
// ---------------------------------------------------------------------------
template<bool PACKED>
__global__ __launch_bounds__(256, 4) void vq_dist(const float* __restrict__ x,
                                                  const uint4* __restrict__ xpk,
                                                  const unsigned short* __restrict__ pk,
                                                  const float* __restrict__ cbn,
                                                  float* __restrict__ rp) {
    int t = threadIdx.x;
    int rowblk = blockIdx.x >> 3;   // 0..255
    int c = blockIdx.x & 7;         // code split
    int l = t & 63, w = t >> 6;
    int G = l >> 4, ci = l & 15;
    int R0 = rowblk * 8 + 2 * w;    // global row-tile (16 rows)

    s8v a0[8], a1[8];
    if (PACKED) {
        const uint4* pa = xpk + (size_t)R0 * 8 * 64 + l;
        #pragma unroll
        for (int s = 0; s < 8; ++s) {
            a0[s] = *(const s8v*)&pa[s * 64];
            a1[s] = *(const s8v*)&pa[512 + s * 64];
        }
    } else {
        int b = rowblk >> 3, p0 = (rowblk & 7) << 7;
        const float* ax = x + (size_t)b * (EMB_DIM * HW) + p0 + 32 * w + ci;
        #pragma unroll
        for (int s = 0; s < 8; ++s) {
            #pragma unroll
            for (int j = 0; j < 8; ++j) {
                int d = 32 * s + 8 * G + j;
                a0[s][j] = (short)f2bf(ax[(size_t)d * HW]);
                a1[s][j] = (short)f2bf(ax[(size_t)d * HW + 16]);
            }
        }
    }

    float mv0[4] = {1e30f, 1e30f, 1e30f, 1e30f};
    float mv1[4] = {1e30f, 1e30f, 1e30f, 1e30f};
    const char* pb = (const char*)pk + (size_t)c * 8 * 8192 + l * 16;
    #pragma unroll 2
    for (int T = 0; T < 8; ++T) {
        const char* pt = pb + (size_t)T * 8192;
        f4v ac0 = {0.f, 0.f, 0.f, 0.f};
        f4v ac1 = {0.f, 0.f, 0.f, 0.f};
        #pragma unroll
        for (int s = 0; s < 8; ++s) {
            s8v bf = *(const s8v*)(pt + s * 1024);
            ac0 = __builtin_amdgcn_mfma_f32_16x16x32_bf16(a0[s], bf, ac0, 0, 0, 0);
            ac1 = __builtin_amdgcn_mfma_f32_16x16x32_bf16(a1[s], bf, ac1, 0, 0, 0);
        }
        float cv = cbn[(c * 8 + T) * 16 + ci];
        #pragma unroll
        for (int rr = 0; rr < 4; ++rr) {
            mv0[rr] = fminf(mv0[rr], cv - 2.f * ac0[rr]);
            mv1[rr] = fminf(mv1[rr], cv - 2.f * ac1[rr]);
        }
    }

    #pragma unroll
    for (int rr = 0; rr < 4; ++rr) {
        #pragma unroll
        for (int m = 1; m < 16; m <<= 1) {
            mv0[rr] = fminf(mv0[rr], __shfl_xor(mv0[rr], m, 64));
            mv1[rr] = fminf(mv1[rr], __shfl_xor(mv1[rr], m, 64));
        }
    }
    if (ci == 0) {
        int base = c * NROWS + R0 * 16;
        #pragma unroll
        for (int rr = 0; rr < 4; ++rr) {
            rp[base +      4 * G + rr] = mv0[rr];
            rp[base + 16 + 4 * G + rr] = mv1[rr];
        }
    }
}

// ---------------------------------------------------------------------------
// fin: min over 8 split-partials per row, fp64 sum + sum(x^2), write scalars.
// Single block => deterministic.
// ---------------------------------------------------------------------------
__global__ __launch_bounds__(1024) void fin_kernel(const float* __restrict__ rp,
                                                   const float* __restrict__ psum,
                                                   float* __restrict__ out) {
    int t = threadIdx.x;
    double s = 0.0;
    for (int i = 0; i < 32; ++i) {
        int r = i * 1024 + t;
        float m = rp[r];
        #pragma unroll
        for (int c = 1; c < 8; ++c) m = fminf(m, rp[c * NROWS + r]);
        s += (double)m;
    }
    s += (double)psum[t] + (double)psum[t + 1024];
    #pragma unroll
    for (int m = 1; m < 64; m <<= 1) s += __shfl_xor(s, m, 64);
    __shared__ double ds[16];
    if ((t & 63) == 0) ds[t >> 6] = s;
    __syncthreads();
    if (t == 0) {
        double tot = 0.0;
        #pragma unroll
        for (int k = 0; k < 16; ++k) tot += ds[k];
        double cl = tot / (double)NELEM;
        out[NELEM + 0] = (float)(1.25 * cl);
        out[NELEM + 1] = (float)cl;
        out[NELEM + 2] = (float)cl;
    }
}

extern "C" void kernel_launch(void* const* d_in, const int* in_sizes, int n_in,
                              void* d_out, int out_size, void* d_ws, size_t ws_size,
                              hipStream_t stream) {
    const float* enc = (const float*)d_in[0];
    const float* cb  = (const float*)d_in[1];
    float* out = (float*)d_out;

    unsigned short* pk  = (unsigned short*)((char*)d_ws + PK_OFF);
    float* cbn  = (float*)((char*)d_ws + CBN_OFF);
    float* psum = (float*)((char*)d_ws + PSUM_OFF);
    float* rp   = (float*)((char*)d_ws + RP_OFF);
    uint4* xpk  = (uint4*)((char*)d_ws + XPK_OFF);

    if (ws_size >= WS_NEED) {
        pack_all<true><<<2112, 256, 0, stream>>>(enc, cb, out, pk, cbn, psum, xpk);
        vq_dist<true><<<2048, 256, 0, stream>>>(enc, xpk, pk, cbn, rp);
    } else {
        pack_all<false><<<2112, 256, 0, stream>>>(enc, cb, out, pk, cbn, psum, xpk);
        vq_dist<false><<<2048, 256, 0, stream>>>(enc, xpk, pk, cbn, rp);
    }
    fin_kernel<<<1, 1024, 0, stream>>>(rp, psum, out);
}

// Round 4
// 108.008 us; speedup vs baseline: 1.6038x; 1.2770x over previous
//
#include <hip/hip_runtime.h>
#include <stdint.h>

typedef short s8v __attribute__((ext_vector_type(8)));   // 8 x bf16 (4 VGPRs)
typedef float f4v __attribute__((ext_vector_type(4)));   // MFMA accumulator

#define EMB_DIM 256
#define HW      1024
#define NROWS   32768
#define NELEM   (NROWS * EMB_DIM)     // 8388608

// ws layout (bytes)
#define PK_OFF   0u          // 512 KB packed bf16 codebook (B-fragments)
#define CBN_OFF  524288u     // 4 KB ||e||^2
#define PSQ_OFF  528384u     // 2 KB per-block sum(x^2) [512]
#define PSM_OFF  530432u     // 2 KB per-block sum(min-dist) [512]

__device__ __forceinline__ unsigned f2bf(float f) {
    union { float f; unsigned u; } c; c.f = f;
    unsigned u = c.u;
    return (u + 0x7FFFu + ((u >> 16) & 1u)) >> 16;   // RNE
}

// ---------------------------------------------------------------------------
// prep_cb: 64 blocks pack the codebook into MFMA B-fragments + ||e||^2.
// pk frag (T,s,lane l=G*16+ci, j) = cb[T*16+ci][32s+8G+j]   (verified layout)
// ---------------------------------------------------------------------------
__global__ __launch_bounds__(256) void prep_cb(const float* __restrict__ cb,
                                               unsigned short* __restrict__ pk,
                                               float* __restrict__ cbn) {
    int T = blockIdx.x, t = threadIdx.x;
    {   // ||e||^2
        int code = t >> 4, seg = t & 15;
        const float* src = cb + (size_t)(T * 16 + code) * EMB_DIM + seg * 16;
        float s2 = 0.f;
        #pragma unroll
        for (int k = 0; k < 4; ++k) {
            float4 v = *(const float4*)(src + 4 * k);
            s2 += v.x * v.x + v.y * v.y + v.z * v.z + v.w * v.w;
        }
        #pragma unroll
        for (int m = 1; m < 16; m <<= 1) s2 += __shfl_xor(s2, m, 64);
        if (seg == 0) cbn[T * 16 + code] = s2;
    }
    #pragma unroll
    for (int it = 0; it < 2; ++it) {
        int idx = t + 256 * it;
        int s = idx >> 6, l = idx & 63, G = l >> 4, ci = l & 15;
        const float* q = cb + (size_t)(T * 16 + ci) * EMB_DIM + 32 * s + 8 * G;
        float4 v0 = *(const float4*)(q);
        float4 v1 = *(const float4*)(q + 4);
        unsigned o0 = f2bf(v0.x) | (f2bf(v0.y) << 16);
        unsigned o1 = f2bf(v0.z) | (f2bf(v0.w) << 16);
        unsigned o2 = f2bf(v1.x) | (f2bf(v1.y) << 16);
        unsigned o3 = f2bf(v1.z) | (f2bf(v1.w) << 16);
        *(uint4*)((char*)pk + (size_t)T * 8192 + (size_t)idx * 16) =
            make_uint4(o0, o1, o2, o3);
    }
}

// ---------------------------------------------------------------------------
// vq_fused: 512 blocks x 256 thr (2 blocks/CU). Block owns 64 rows.
// Phase 1: copy x->out, sum(x^2), transpose-convert rows into bf16 A-frags
//          in LDS (layout identical to the verified xpk layout).
// Phase 2: wave w holds ALL 4 row-tiles' A-frags in registers and scans its
//          distinct code-quarter (16 tiles): each B-load feeds 4 independent
//          MFMA chains. Per-row mins combined across waves via LDS; block
//          writes two fp32 partial sums. No barriers in the hot loop.
// ---------------------------------------------------------------------------
__global__ __launch_bounds__(256, 2) void vq_fused(const float* __restrict__ x,
                                                   float* __restrict__ out,
                                                   const unsigned short* __restrict__ pk,
                                                   const float* __restrict__ cbn,
                                                   float* __restrict__ psq,
                                                   float* __restrict__ psm) {
    __shared__ float smemf[64 * 69];     // fp32 chunk staging (pad 69)
    __shared__ uint4 frag[4 * 8 * 64];   // 32 KB bf16 A-fragments
    __shared__ float mloc[4][64];        // per-wave per-row mins
    __shared__ float red[4];             // per-wave sum(x^2)

    int t = threadIdx.x;
    int blk = blockIdx.x;
    int b = blk >> 4, p0 = (blk & 15) << 6;   // 64 rows: [p0, p0+64) of batch b
    const float* xb = x   + (size_t)b * (EMB_DIM * HW) + p0;
    float*       ob = out + (size_t)b * (EMB_DIM * HW) + p0;

    int l = t & 63, w = t >> 6;
    int G = l >> 4, ci = l & 15;

    // ---- phase 1: copy + sq + transpose to A-frags (4 chunks of 64 dims) ----
    float sq = 0.f;
    int pq = t & 15, dd = t >> 4;
    for (int kd = 0; kd < 4; ++kd) {
        #pragma unroll
        for (int c2 = 0; c2 < 4; ++c2) {
            int dl = dd + 16 * c2;              // local dim in chunk
            size_t off = (size_t)(kd * 64 + dl) * HW + 4 * pq;
            float4 v = *(const float4*)(xb + off);
            *(float4*)(ob + off) = v;
            sq += v.x * v.x + v.y * v.y + v.z * v.z + v.w * v.w;
            float* dst = &smemf[dl * 69 + 4 * pq];
            dst[0] = v.x; dst[1] = v.y; dst[2] = v.z; dst[3] = v.w;
        }
        __syncthreads();
        #pragma unroll
        for (int it = 0; it < 2; ++it) {
            int f = t + 256 * it;
            int fl = f & 63, sL = (f >> 6) & 1, R = f >> 7;
            int fG = fl >> 4, fci = fl & 15;
            const float* q = &smemf[(32 * sL + 8 * fG) * 69 + 16 * R + fci];
            unsigned o0 = f2bf(q[0])   | (f2bf(q[69])  << 16);
            unsigned o1 = f2bf(q[138]) | (f2bf(q[207]) << 16);
            unsigned o2 = f2bf(q[276]) | (f2bf(q[345]) << 16);
            unsigned o3 = f2bf(q[414]) | (f2bf(q[483]) << 16);
            frag[(R * 8 + 2 * kd + sL) * 64 + fl] = make_uint4(o0, o1, o2, o3);
        }
        __syncthreads();
    }
    #pragma unroll
    for (int m = 1; m < 64; m <<= 1) sq += __shfl_xor(sq, m, 64);
    if (l == 0) red[w] = sq;

    // ---- phase 2: A-frags (all 4 row-tiles) into registers ----
    s8v a[4][8];
    #pragma unroll
    for (int R = 0; R < 4; ++R)
        #pragma unroll
        for (int s = 0; s < 8; ++s)
            a[R][s] = *(const s8v*)&frag[(R * 8 + s) * 64 + l];

    float mv[4][4];
    #pragma unroll
    for (int R = 0; R < 4; ++R)
        #pragma unroll
        for (int r = 0; r < 4; ++r) mv[R][r] = 1e30f;

    // wave w scans code tiles w*16 .. w*16+15 (its distinct quarter)
    const char* pb = (const char*)pk + (size_t)(w * 16) * 8192 + (size_t)l * 16;
    #pragma unroll 2
    for (int T = 0; T < 16; ++T) {
        const char* pt = pb + (size_t)T * 8192;
        f4v ac0 = {0.f,0.f,0.f,0.f}, ac1 = {0.f,0.f,0.f,0.f};
        f4v ac2 = {0.f,0.f,0.f,0.f}, ac3 = {0.f,0.f,0.f,0.f};
        #pragma unroll
        for (int s = 0; s < 8; ++s) {
            s8v bf = *(const s8v*)(pt + s * 1024);
            ac0 = __builtin_amdgcn_mfma_f32_16x16x32_bf16(a[0][s], bf, ac0, 0, 0, 0);
            ac1 = __builtin_amdgcn_mfma_f32_16x16x32_bf16(a[1][s], bf, ac1, 0, 0, 0);
            ac2 = __builtin_amdgcn_mfma_f32_16x16x32_bf16(a[2][s], bf, ac2, 0, 0, 0);
            ac3 = __builtin_amdgcn_mfma_f32_16x16x32_bf16(a[3][s], bf, ac3, 0, 0, 0);
        }
        float cv = cbn[(w * 16 + T) * 16 + ci];
        #pragma unroll
        for (int r = 0; r < 4; ++r) {
            mv[0][r] = fminf(mv[0][r], cv - 2.f * ac0[r]);
            mv[1][r] = fminf(mv[1][r], cv - 2.f * ac1[r]);
            mv[2][r] = fminf(mv[2][r], cv - 2.f * ac2[r]);
            mv[3][r] = fminf(mv[3][r], cv - 2.f * ac3[r]);
        }
    }

    // ---- min over the 16 code-lanes; stash per-wave row mins in LDS ----
    #pragma unroll
    for (int R = 0; R < 4; ++R)
        #pragma unroll
        for (int r = 0; r < 4; ++r) {
            float v = mv[R][r];
            #pragma unroll
            for (int m = 1; m < 16; m <<= 1) v = fminf(v, __shfl_xor(v, m, 64));
            mv[R][r] = v;
        }
    if (ci == 0) {
        #pragma unroll
        for (int R = 0; R < 4; ++R)
            #pragma unroll
            for (int r = 0; r < 4; ++r)
                mloc[w][16 * R + 4 * G + r] = mv[R][r];
    }
    __syncthreads();

    // ---- combine: final per-row min over 4 waves, sum 64 rows ----
    if (t < 64) {
        float m = fminf(fminf(mloc[0][t], mloc[1][t]),
                        fminf(mloc[2][t], mloc[3][t]));
        #pragma unroll
        for (int mm = 1; mm < 64; mm <<= 1) m += __shfl_xor(m, mm, 64);
        if (t == 0) {
            psm[blk] = m;
            psq[blk] = red[0] + red[1] + red[2] + red[3];
        }
    }
}

// ---------------------------------------------------------------------------
// fin: 512 threads, one block, deterministic fp64 sum of per-block partials.
// ---------------------------------------------------------------------------
__global__ __launch_bounds__(512) void fin_kernel(const float* __restrict__ psm,
                                                  const float* __restrict__ psq,
                                                  float* __restrict__ out) {
    int t = threadIdx.x;
    double s = (double)psm[t] + (double)psq[t];
    #pragma unroll
    for (int m = 1; m < 64; m <<= 1) s += __shfl_xor(s, m, 64);
    __shared__ double ds[8];
    if ((t & 63) == 0) ds[t >> 6] = s;
    __syncthreads();
    if (t == 0) {
        double tot = 0.0;
        #pragma unroll
        for (int k = 0; k < 8; ++k) tot += ds[k];
        double cl = tot / (double)NELEM;
        out[NELEM + 0] = (float)(1.25 * cl);
        out[NELEM + 1] = (float)cl;
        out[NELEM + 2] = (float)cl;
    }
}

extern "C" void kernel_launch(void* const* d_in, const int* in_sizes, int n_in,
                              void* d_out, int out_size, void* d_ws, size_t ws_size,
                              hipStream_t stream) {
    const float* enc = (const float*)d_in[0];
    const float* cb  = (const float*)d_in[1];
    float* out = (float*)d_out;

    unsigned short* pk = (unsigned short*)((char*)d_ws + PK_OFF);
    float* cbn = (float*)((char*)d_ws + CBN_OFF);
    float* psq = (float*)((char*)d_ws + PSQ_OFF);
    float* psm = (float*)((char*)d_ws + PSM_OFF);

    prep_cb<<<64, 256, 0, stream>>>(cb, pk, cbn);
    vq_fused<<<512, 256, 0, stream>>>(enc, out, pk, cbn, psq, psm);
    fin_kernel<<<1, 512, 0, stream>>>(psm, psq, out);
}